// Round 20
// baseline (88.059 us; speedup 1.0000x reference)
//
#include <hip/hip_runtime.h>

typedef unsigned char u8;
typedef float f32x4 __attribute__((ext_vector_type(4)));
typedef _Float16 f16x8 __attribute__((ext_vector_type(8)));

#define DIM 128
#define TM  128
// r17 lesson: NEVER wrap the MFMA block (acc/bh live state) in a runtime
// loop -- the compiler demotes the arrays to scratch (~1.4KB/thread of HBM
// traffic). Every mlp_wave call below is straight-line from kernel entry
// (conditional branches are fine; loops are not).

__device__ __forceinline__ float fast_tanh(float x) {
    // tanh(x) = 1 - 2/(exp2(2x*log2e)+1); exact +-1 saturation via inf->0
    float e = __builtin_amdgcn_exp2f(x * 2.885390081777927f);
    return 1.0f - 2.0f * __builtin_amdgcn_rcpf(e + 1.0f);
}
__device__ __forceinline__ float fast_sigmoid(float x) {
    float e = __builtin_amdgcn_exp2f(x * -1.4426950408889634f);
    return __builtin_amdgcn_rcpf(1.0f + e);
}

// stage W2^T (fp16, XOR-swizzled 16B chunks) into LDS; any thread count
__device__ __forceinline__ void stage_w2(const float* __restrict__ W2,
                                         _Float16* sW2T, int tid, int nt) {
    for (int chunk = tid; chunk < 2048; chunk += nt) {
        int n = chunk & 127, ko = chunk >> 7;
        f16x8 v;
        #pragma unroll
        for (int qq = 0; qq < 8; ++qq)
            v[qq] = (_Float16)W2[(ko * 8 + qq) * DIM + n];   // coalesced over n
        int slot = ko ^ (n & 15);
        *(f16x8*)&sW2T[n * DIM + slot * 8] = v;
    }
}

// one wave: 32 points (2 A-frags) x 128 dims; b2 folded into acc init.
// rs[mf][rg] = sum_c tanh(h2)*W3, lane-reduced (valid on all lanes).
// C/D: point-row = mf*16 + lg*4 + rg.
__device__ __forceinline__ void mlp_wave(
    const float xs[2], const float ys[2], const _Float16* sW2T,
    const float* __restrict__ W1, const float* __restrict__ b1,
    const float* __restrict__ b2, const float* __restrict__ W3,
    int lg, int l15, float rs[2][4])
{
    f32x4 acc[2][8];
    #pragma unroll
    for (int nf = 0; nf < 8; ++nf) {
        float b2v = b2[nf * 16 + l15];
        acc[0][nf] = (f32x4)(b2v);
        acc[1][nf] = (f32x4)(b2v);
    }
    #pragma unroll
    for (int kf = 0; kf < 4; ++kf) {
        const int kbase = kf * 32 + lg * 8;
        f16x8 bh[8];
        #pragma unroll
        for (int nf = 0; nf < 8; ++nf) {
            int cc = nf * 16 + l15;
            int slot = (kf * 4 + lg) ^ l15;   // matches stage_w2 swizzle
            bh[nf] = *(const f16x8*)&sW2T[cc * DIM + slot * 8];
        }
        f32x4 wxa = *(const f32x4*)&W1[kbase];
        f32x4 wxb = *(const f32x4*)&W1[kbase + 4];
        f32x4 wya = *(const f32x4*)&W1[DIM + kbase];
        f32x4 wyb = *(const f32x4*)&W1[DIM + kbase + 4];
        f32x4 b1a = *(const f32x4*)&b1[kbase];
        f32x4 b1b = *(const f32x4*)&b1[kbase + 4];
        f16x8 ah[2];
        #pragma unroll
        for (int mf = 0; mf < 2; ++mf) {
            float x = xs[mf], y = ys[mf];
            #pragma unroll
            for (int qq = 0; qq < 4; ++qq)
                ah[mf][qq] = (_Float16)fast_tanh(fmaf(x, wxa[qq], fmaf(y, wya[qq], b1a[qq])));
            #pragma unroll
            for (int qq = 0; qq < 4; ++qq)
                ah[mf][4 + qq] = (_Float16)fast_tanh(fmaf(x, wxb[qq], fmaf(y, wyb[qq], b1b[qq])));
        }
        #pragma unroll
        for (int nf = 0; nf < 8; ++nf)
            #pragma unroll
            for (int mf = 0; mf < 2; ++mf)
                acc[mf][nf] = __builtin_amdgcn_mfma_f32_16x16x32_f16(ah[mf], bh[nf], acc[mf][nf], 0, 0, 0);
    }
    #pragma unroll
    for (int mf = 0; mf < 2; ++mf)
        #pragma unroll
        for (int rg = 0; rg < 4; ++rg) rs[mf][rg] = 0.0f;
    #pragma unroll
    for (int nf = 0; nf < 8; ++nf) {
        float w3v = W3[nf * 16 + l15];
        #pragma unroll
        for (int mf = 0; mf < 2; ++mf)
            #pragma unroll
            for (int rg = 0; rg < 4; ++rg)
                rs[mf][rg] += fast_tanh(acc[mf][nf][rg]) * w3v;
    }
    #pragma unroll
    for (int mf = 0; mf < 2; ++mf)
        #pragma unroll
        for (int rg = 0; rg < 4; ++rg) {
            float v = rs[mf][rg];
            v += __shfl_xor(v, 1);
            v += __shfl_xor(v, 2);
            v += __shfl_xor(v, 4);
            v += __shfl_xor(v, 8);
            rs[mf][rg] = v;
        }
}

// ---- dense MLP eval of an RxR grid (R-1 power of two); straight-line ----
__global__ __launch_bounds__(256, 4) void eval_grid(
    const float* __restrict__ W1, const float* __restrict__ b1,
    const float* __restrict__ W2, const float* __restrict__ b2,
    const float* __restrict__ W3, const float* __restrict__ b3,
    const float* __restrict__ bmin, const float* __restrict__ bmax,
    float* __restrict__ out, int R)
{
    __shared__ __align__(16) _Float16 sW2T[DIM * DIM];   // 32 KB
    const int N = R * R;
    const int tid = threadIdx.x;
    const int m0 = blockIdx.x * TM;
    stage_w2(W2, sW2T, tid, 256);

    const int w = tid >> 6, lane = tid & 63;
    const int l15 = lane & 15, lg = lane >> 4;

    const float inv = 1.0f / (float)(R - 1);   // power-of-two -> exact
    const float bx0 = bmin[0], by0 = bmin[1];
    const float sx = bmax[0] - bx0, sy = bmax[1] - by0;
    float xs[2], ys[2];
    #pragma unroll
    for (int mf = 0; mf < 2; ++mf) {
        int pi = m0 + w * 32 + mf * 16 + l15;
        int pg = (pi < N) ? pi : N - 1;
        int gi = pg / R, gj = pg - gi * R;
        xs[mf] = bx0 + (float)gj * inv * sx;
        ys[mf] = by0 + (float)gi * inv * sy;
    }
    __syncthreads();

    float rs[2][4];
    mlp_wave(xs, ys, sW2T, W1, b1, b2, W3, lg, l15, rs);
    if (l15 == 0) {
        float b3v = b3[0];
        #pragma unroll
        for (int mf = 0; mf < 2; ++mf)
            #pragma unroll
            for (int rg = 0; rg < 4; ++rg) {
                int po = m0 + w * 32 + mf * 16 + lg * 4 + rg;
                if (po < N) out[po] = fast_sigmoid(rs[mf][rg] + b3v);
            }
    }
}

// ---- one refinement level on a 24x24 window, one thread per cell ----
#define HWF 24
#define NTF 576
template<bool FIRST>
__device__ __forceinline__ void run_level(
    int c, int li, int lj, int oi0, int oj0, int R,
    const float* __restrict__ qbuf, int qpitch, int qs,
    const float* __restrict__ q257, int pOi, int pOj,
    const float* sOccP, const u8* sCalP,
    u8* sRaw, u8* sCfA, u8* sCfB,
    float& occR, bool& calR)
{
    const float BAL = 0.5f;
    const int fi = oi0 + li, fj = oj0 + lj;
    const bool inG = (fi >= 0 && fi < R && fj >= 0 && fj < R);
    float occ = 0.5f, qv = 0.5f;
    u8 rw = 0; bool cal = false;
    if (inG) qv = qbuf[(fi * qs) * qpitch + fj * qs];   // issued early, used late
    if (inG) {
        int ip = fi >> 1, jp = fj >> 1;
        int oi = fi & 1, oj = fj & 1;
        float tl = FIRST ? q257[(ip * 8) * 257 + jp * 8]
                         : sOccP[(ip - pOi) * HWF + (jp - pOj)];
        bool b;
        if (!oi && !oj) { occ = tl; b = false; }
        else if (oi && !oj) {
            float bl = FIRST ? q257[((ip + 1) * 8) * 257 + jp * 8]
                             : sOccP[(ip + 1 - pOi) * HWF + (jp - pOj)];
            occ = 0.5f * (tl + bl);
            b = (tl > BAL) != (bl > BAL);
        } else if (!oi && oj) {
            float tr = FIRST ? q257[(ip * 8) * 257 + (jp + 1) * 8]
                             : sOccP[(ip - pOi) * HWF + (jp + 1 - pOj)];
            occ = 0.5f * (tl + tr);
            b = (tl > BAL) != (tr > BAL);
        } else {
            float bl = FIRST ? q257[((ip + 1) * 8) * 257 + jp * 8]
                             : sOccP[(ip + 1 - pOi) * HWF + (jp - pOj)];
            float tr = FIRST ? q257[(ip * 8) * 257 + (jp + 1) * 8]
                             : sOccP[(ip - pOi) * HWF + (jp + 1 - pOj)];
            float br = FIRST ? q257[((ip + 1) * 8) * 257 + (jp + 1) * 8]
                             : sOccP[(ip + 1 - pOi) * HWF + (jp + 1 - pOj)];
            occ = 0.5f * (0.5f * (tl + bl) + 0.5f * (tr + br));  // exact _up2 order
            bool m0 = tl > BAL, m1 = bl > BAL, m2 = tr > BAL, m3 = br > BAL;
            b = (m0 | m1 | m2 | m3) && !(m0 & m1 & m2 & m3);
        }
        rw = b ? 1 : 0;
        if (((fi | fj) & 1) == 0)
            cal = FIRST ? true : (sCalP[(ip - pOi) * HWF + (jp - pOj)] != 0);
    }
    sRaw[c] = rw; sCfA[c] = 0; sCfB[c] = 0;

    if (__syncthreads_or(rw)) {
        u8 cf = 0;
        if (li >= 1 && li < HWF - 1 && lj >= 1 && lj < HWF - 1 && inG) {
            bool b = false;
            #pragma unroll
            for (int di = -1; di <= 1; ++di)
                #pragma unroll
                for (int dj = -1; dj <= 1; ++dj)
                    if (sRaw[(li + di) * HWF + (lj + dj)]) b = true;
            b = b && !cal;
            cf = (b && (occ - BAL) * (qv - BAL) < 0.0f) ? 1 : 0;
            if (b) { occ = qv; cal = true; }
            sCfA[c] = cf;
        }
        int haveCf = __syncthreads_or((int)cf);

        #pragma unroll
        for (int it = 0; it < 3; ++it) {
            if (!haveCf) break;
            const u8* cin = (it & 1) ? sCfB : sCfA;
            u8* cout      = (it & 1) ? sCfA : sCfB;
            int lo = 2 + it, hi = HWF - 2 - it;
            u8 nc = 0;
            if (li >= lo && li < hi && lj >= lo && lj < hi && inG) {
                bool any = false;
                #pragma unroll
                for (int di = -1; di <= 1; ++di)
                    #pragma unroll
                    for (int dj = -1; dj <= 1; ++dj)
                        if (cin[(li + di) * HWF + (lj + dj)]) any = true;
                bool cand = any && !cal;
                nc = (cand && (occ - BAL) * (qv - BAL) < 0.0f) ? 1 : 0;
                if (cand) { occ = qv; cal = true; }
                cout[c] = nc;
            }
            haveCf = __syncthreads_or((int)nc);
        }
    }
    occR = occ; calR = cal;
}

// ---- levels 1-3 fused, one block per 16x16 tile of the 257 grid ----
// Origins: o3=16b-4 (257), o2=8b-6 (129), o1=4b-7 (65); each level's parent
// reads land inside the previous window's exact core [4,20).
__global__ __launch_bounds__(NTF) void levels123_fused(
    const float* __restrict__ q257,
    float* __restrict__ occ257, u8* __restrict__ cal257)
{
    __shared__ float sOcc[NTF];
    __shared__ u8 sCal[NTF], sRaw[NTF], sCfA[NTF], sCfB[NTF];
    const int bi = blockIdx.x / 17, bj = blockIdx.x - bi * 17;
    const int c = threadIdx.x;
    const int li = c / HWF, lj = c - li * HWF;
    float occ; bool cal;

    run_level<true>(c, li, lj, 4 * bi - 7, 4 * bj - 7, 65,
                    q257, 257, 4, q257, 0, 0,
                    sOcc, sCal, sRaw, sCfA, sCfB, occ, cal);
    sOcc[c] = occ; sCal[c] = cal ? 1 : 0;
    __syncthreads();
    run_level<false>(c, li, lj, 8 * bi - 6, 8 * bj - 6, 129,
                     q257, 257, 2, q257, 4 * bi - 7, 4 * bj - 7,
                     sOcc, sCal, sRaw, sCfA, sCfB, occ, cal);
    sOcc[c] = occ; sCal[c] = cal ? 1 : 0;
    __syncthreads();
    run_level<false>(c, li, lj, 16 * bi - 4, 16 * bj - 4, 257,
                     q257, 257, 1, q257, 8 * bi - 6, 8 * bj - 6,
                     sOcc, sCal, sRaw, sCfA, sCfB, occ, cal);

    const int fi = 16 * bi - 4 + li, fj = 16 * bj - 4 + lj;
    if (li >= 4 && li < 20 && lj >= 4 && lj < 20 && fi < 257 && fj < 257) {
        occ257[fi * 257 + fj] = occ;
        cal257[fi * 257 + fj] = cal ? 1 : 0;
    }
}

// ---- level 4 + in-tile fine eval, one block per 16x16 tile of 513 ----
// Phase 1 computes raw4 from occ257. If no raw in the window: write-through,
// no MLP at all. Else: stage W2, evaluate ALL 576 window cells via TWO
// straight-line mlp_wave calls (9 waves x 32 pts each), sQ in LDS, then the
// standard resolve (boundary + 3 conflict iters) reading sQ.
__global__ __launch_bounds__(NTF) void level4_fused(
    const float* __restrict__ W1, const float* __restrict__ b1,
    const float* __restrict__ W2, const float* __restrict__ b2,
    const float* __restrict__ W3, const float* __restrict__ b3,
    const float* __restrict__ bmin, const float* __restrict__ bmax,
    const float* __restrict__ occP, const u8* __restrict__ calcP,
    float* __restrict__ out)
{
    __shared__ __align__(16) _Float16 sW2T[DIM * DIM];   // 32 KB
    __shared__ float sQ[NTF];
    __shared__ u8 sRaw[NTF], sCfA[NTF], sCfB[NTF];
    const int bi = blockIdx.x / 33, bj = blockIdx.x - bi * 33;
    const int fi0 = bi * 16 - 4, fj0 = bj * 16 - 4;
    const int tid = threadIdx.x;
    const int c = tid;
    const int li = c / HWF, lj = c - li * HWF;
    const int fi = fi0 + li, fj = fj0 + lj;
    const bool inG = (fi >= 0 && fi < 513 && fj >= 0 && fj < 513);
    const float BAL = 0.5f;

    // phase 1: upsample from occ257 + raw + inherited calc (registers)
    float occ = 0.5f;
    u8 rw = 0; bool cal = false;
    if (inG) {
        int ip = fi >> 1, jp = fj >> 1;
        float tl = occP[ip * 257 + jp];
        int oi = fi & 1, oj = fj & 1;
        bool b;
        if (!oi && !oj) { occ = tl; b = false; }
        else if (oi && !oj) {
            float bl = occP[(ip + 1) * 257 + jp];
            occ = 0.5f * (tl + bl);
            b = (tl > BAL) != (bl > BAL);
        } else if (!oi && oj) {
            float tr = occP[ip * 257 + jp + 1];
            occ = 0.5f * (tl + tr);
            b = (tl > BAL) != (tr > BAL);
        } else {
            float bl = occP[(ip + 1) * 257 + jp];
            float tr = occP[ip * 257 + jp + 1];
            float br = occP[(ip + 1) * 257 + jp + 1];
            occ = 0.5f * (0.5f * (tl + bl) + 0.5f * (tr + br));  // exact _up2 order
            bool m0 = tl > BAL, m1 = bl > BAL, m2 = tr > BAL, m3 = br > BAL;
            b = (m0 | m1 | m2 | m3) && !(m0 & m1 & m2 & m3);
        }
        rw = b ? 1 : 0;
        if (((fi | fj) & 1) == 0) cal = calcP[ip * 257 + jp] != 0;
    }
    sRaw[c] = rw; sCfA[c] = 0; sCfB[c] = 0;

    if (!__syncthreads_or(rw)) {
        // no boundary near this tile: q never read -> pure write-through
        if (li >= 4 && li < 20 && lj >= 4 && lj < 20 && inG)
            out[fi * 513 + fj] = occ;
        return;
    }

    // ---- in-tile MLP eval of all 576 window cells (two straight-line calls) ----
    stage_w2(W2, sW2T, tid, NTF);
    __syncthreads();

    const int w = tid >> 6, lane = tid & 63;   // w = 0..8 (9 waves)
    const int l15 = lane & 15, lg = lane >> 4;
    const float inv = 1.0f / 512.0f;
    const float bx0 = bmin[0], by0 = bmin[1];
    const float sx = bmax[0] - bx0, sy = bmax[1] - by0;
    const float b3v = b3[0];

    {   // call 0: cells [0, 288)
        float xs[2], ys[2];
        #pragma unroll
        for (int mf = 0; mf < 2; ++mf) {
            int cell = w * 32 + mf * 16 + l15;
            int gi = fi0 + cell / 24, gj = fj0 + cell % 24;
            gi = gi < 0 ? 0 : (gi > 512 ? 512 : gi);
            gj = gj < 0 ? 0 : (gj > 512 ? 512 : gj);
            xs[mf] = bx0 + (float)gj * inv * sx;
            ys[mf] = by0 + (float)gi * inv * sy;
        }
        float rs[2][4];
        mlp_wave(xs, ys, sW2T, W1, b1, b2, W3, lg, l15, rs);
        if (l15 == 0) {
            #pragma unroll
            for (int mf = 0; mf < 2; ++mf)
                #pragma unroll
                for (int rg = 0; rg < 4; ++rg) {
                    int cell = w * 32 + mf * 16 + lg * 4 + rg;
                    sQ[cell] = fast_sigmoid(rs[mf][rg] + b3v);
                }
        }
    }
    {   // call 1: cells [288, 576)
        float xs[2], ys[2];
        #pragma unroll
        for (int mf = 0; mf < 2; ++mf) {
            int cell = 288 + w * 32 + mf * 16 + l15;
            int gi = fi0 + cell / 24, gj = fj0 + cell % 24;
            gi = gi < 0 ? 0 : (gi > 512 ? 512 : gi);
            gj = gj < 0 ? 0 : (gj > 512 ? 512 : gj);
            xs[mf] = bx0 + (float)gj * inv * sx;
            ys[mf] = by0 + (float)gi * inv * sy;
        }
        float rs[2][4];
        mlp_wave(xs, ys, sW2T, W1, b1, b2, W3, lg, l15, rs);
        if (l15 == 0) {
            #pragma unroll
            for (int mf = 0; mf < 2; ++mf)
                #pragma unroll
                for (int rg = 0; rg < 4; ++rg) {
                    int cell = 288 + w * 32 + mf * 16 + lg * 4 + rg;
                    sQ[cell] = fast_sigmoid(rs[mf][rg] + b3v);
                }
        }
    }
    __syncthreads();
    const float qv = sQ[c];

    // ---- resolve: boundary + 3 conflict iterations ----
    {
        u8 cf = 0;
        if (li >= 1 && li < HWF - 1 && lj >= 1 && lj < HWF - 1 && inG) {
            bool b = false;
            #pragma unroll
            for (int di = -1; di <= 1; ++di)
                #pragma unroll
                for (int dj = -1; dj <= 1; ++dj)
                    if (sRaw[(li + di) * HWF + (lj + dj)]) b = true;
            b = b && !cal;
            cf = (b && (occ - BAL) * (qv - BAL) < 0.0f) ? 1 : 0;
            if (b) { occ = qv; cal = true; }
            sCfA[c] = cf;
        }
        int haveCf = __syncthreads_or((int)cf);

        #pragma unroll
        for (int it = 0; it < 3; ++it) {
            if (!haveCf) break;
            const u8* cin = (it & 1) ? sCfB : sCfA;
            u8* cout      = (it & 1) ? sCfA : sCfB;
            int lo = 2 + it, hi = HWF - 2 - it;
            u8 nc = 0;
            if (li >= lo && li < hi && lj >= lo && lj < hi && inG) {
                bool any = false;
                #pragma unroll
                for (int di = -1; di <= 1; ++di)
                    #pragma unroll
                    for (int dj = -1; dj <= 1; ++dj)
                        if (cin[(li + di) * HWF + (lj + dj)]) any = true;
                bool cand = any && !cal;
                nc = (cand && (occ - BAL) * (qv - BAL) < 0.0f) ? 1 : 0;
                if (cand) { occ = qv; cal = true; }
                cout[c] = nc;
            }
            haveCf = __syncthreads_or((int)nc);
        }
    }

    if (li >= 4 && li < 20 && lj >= 4 && lj < 20 && inG)
        out[fi * 513 + fj] = occ;
}

extern "C" void kernel_launch(void* const* d_in, const int* in_sizes, int n_in,
                              void* d_out, int out_size, void* d_ws, size_t ws_size,
                              hipStream_t stream) {
    const float* W1   = (const float*)d_in[0];
    const float* b1   = (const float*)d_in[1];
    const float* W2   = (const float*)d_in[2];
    const float* b2   = (const float*)d_in[3];
    const float* W3   = (const float*)d_in[4];
    const float* b3   = (const float*)d_in[5];
    const float* bmin = (const float*)d_in[6];
    const float* bmax = (const float*)d_in[7];

    const int N257 = 257 * 257;
    float* q257   = (float*)d_ws;
    float* occ257 = q257 + N257;
    u8*    cal257 = (u8*)(occ257 + N257);
    float* out    = (float*)d_out;

    // 1) dense eval at 257 (covers all q-reads of levels 1-3 bit-exactly)
    eval_grid<<<(N257 + TM - 1) / TM, 256, 0, stream>>>(
        W1, b1, W2, b2, W3, b3, bmin, bmax, q257, 257);

    // 2) levels 1-3 fused -> refined occ257 + cal257
    levels123_fused<<<17 * 17, NTF, 0, stream>>>(q257, occ257, cal257);

    // 3) level 4 with in-tile masked fine eval -> output
    level4_fused<<<33 * 33, NTF, 0, stream>>>(
        W1, b1, W2, b2, W3, b3, bmin, bmax, occ257, cal257, out);
}